// Round 9
// baseline (123.858 us; speedup 1.0000x reference)
//
#include <hip/hip_runtime.h>
#include <hip/hip_bf16.h>

#define IW    4096
#define OW    4096
#define PC    64
#define BATCH 1024
#define BC    8            // batch-chunk staged in LDS: 4096 rows x 8 batches x bf16 = 64 KB
#define NCHUNK (BATCH / BC)   // 128
#define OSPLIT 4              // output quarters per chunk -> grid 512 = 2 blocks/CU

__device__ __forceinline__ float sigmoidf_(float x) {
    return 1.0f / (1.0f + __expf(-x));
}

__device__ __forceinline__ unsigned short f2bfbits(float f) {
    union { __hip_bfloat16 h; unsigned short u; } cv;
    cv.h = __float2bfloat16(f);   // RNE
    return cv.u;
}

// K1: x [BATCH][IW] f32 -> xC chunk-major: xC[chunk][IW][BC] bf16.
// 64x64 transpose tile spans 8 chunks; each ushort4 (4 batches) stays in one.
__global__ __launch_bounds__(256) void k_transpose_cast(
        const float* __restrict__ x, unsigned short* __restrict__ xC) {
    __shared__ float tile[64][65];          // [c_local][b_local], +1 pad
    const int c0 = blockIdx.x * 64;         // input-width tile
    const int b0 = blockIdx.y * 64;         // batch tile
    const int t  = threadIdx.x;
    const int r  = t >> 4;                  // 0..15
    const int s  = t & 15;                  // 0..15
    #pragma unroll
    for (int it = 0; it < 4; ++it) {
        const int row = r + 16 * it;        // batch row in tile
        const float4 v = *reinterpret_cast<const float4*>(
            x + (size_t)(b0 + row) * IW + c0 + s * 4);
        tile[s * 4 + 0][row] = v.x;
        tile[s * 4 + 1][row] = v.y;
        tile[s * 4 + 2][row] = v.z;
        tile[s * 4 + 3][row] = v.w;
    }
    __syncthreads();
    const int b4    = b0 + s * 4;           // first batch of this thread's quad
    const int chunk = b4 >> 3;
    const int pos   = b4 & 7;               // 0 or 4
    unsigned short* dst = xC + (size_t)chunk * IW * BC + pos;
    #pragma unroll
    for (int it = 0; it < 4; ++it) {
        const int c = r + 16 * it;          // c_local
        ushort4 o;
        o.x = f2bfbits(tile[c][s * 4 + 0]);
        o.y = f2bfbits(tile[c][s * 4 + 1]);
        o.z = f2bfbits(tile[c][s * 4 + 2]);
        o.w = f2bfbits(tile[c][s * 4 + 3]);
        *reinterpret_cast<ushort4*>(dst + (size_t)(c0 + c) * BC) = o;
    }
}

// P0: transpose params to p-major: pairT[p*OW + o] = {sel[o][p]*16, f32 sigmoid(w[o][p])}
__global__ __launch_bounds__(256) void k_prep_params(
        const int* __restrict__ sel, const float* __restrict__ wts,
        int2* __restrict__ pairT) {
    const int tid = blockIdx.x * 256 + threadIdx.x;   // 0 .. OW*PC-1
    const int o = tid & (OW - 1);
    const int p = tid >> 12;
    const int gi = o * PC + p;
    int2 e;
    e.x = sel[gi] * (BC * 2);               // byte offset of row in LDS chunk
    e.y = __float_as_int(sigmoidf_(wts[gi]));
    pairT[(size_t)p * OW + o] = e;
}

// K2: LDS-staged gather. Grid 512 = NCHUNK(128) x OSPLIT(4); 1024 threads.
// Block stages chunk (64 KB) in LDS, then each wave computes 2x32 outputs:
// lane = (oloc = lane>>1, half = lane&1); serial p-loop, ds_read_b64 pulls
// 4 batches of row sel[o][p]; params stream from pairT (coalesced, L2-hot).
// No cross-lane reduction.
__global__ __launch_bounds__(1024, 8) void k_gather_lds(
        const unsigned short* __restrict__ xC,
        const int2* __restrict__ pairT,
        const float* __restrict__ biases,
        unsigned short* __restrict__ outT) {
    __shared__ unsigned short lds[IW * BC];           // 64 KB
    const int bid   = blockIdx.x;
    const int chunk = bid >> 2;                       // 0..127
    const int og    = bid & 3;                        // output quarter
    const int t     = threadIdx.x;
    // stage chunk: 4 rounds x 1024 threads x 16 B = 64 KB, coalesced
    {
        const uint4* src = reinterpret_cast<const uint4*>(xC + (size_t)chunk * IW * BC);
        uint4* dst = reinterpret_cast<uint4*>(lds);
        #pragma unroll
        for (int it = 0; it < 4; ++it)
            dst[t + 1024 * it] = src[t + 1024 * it];
    }
    __syncthreads();
    const int wv   = t >> 6;                          // 0..15
    const int lane = t & 63;
    const int oloc = lane >> 1;                       // 0..31
    const int half = lane & 1;
    const char* ldsb = (const char*)lds + half * 8;
    #pragma unroll 1
    for (int g2 = 0; g2 < 2; ++g2) {
        const int o = og * 1024 + (wv * 2 + g2) * 32 + oloc;
        const int2* pp = pairT + o;
        float a0 = 0.f, a1 = 0.f, a2 = 0.f, a3 = 0.f;
        #pragma unroll 4
        for (int p = 0; p < PC; ++p) {
            const int2 pr = pp[(size_t)p * OW];
            const uint2 d = *reinterpret_cast<const uint2*>(ldsb + pr.x);
            const float wa = __int_as_float(pr.y);
            a0 = fmaf(wa, __uint_as_float(d.x << 16),         a0);
            a1 = fmaf(wa, __uint_as_float(d.x & 0xffff0000u), a1);
            a2 = fmaf(wa, __uint_as_float(d.y << 16),         a2);
            a3 = fmaf(wa, __uint_as_float(d.y & 0xffff0000u), a3);
        }
        const float bo = biases[o];
        ushort4 ov;
        ov.x = f2bfbits(sigmoidf_(a0 - bo));
        ov.y = f2bfbits(sigmoidf_(a1 - bo));
        ov.z = f2bfbits(sigmoidf_(a2 - bo));
        ov.w = f2bfbits(sigmoidf_(a3 - bo));
        *reinterpret_cast<ushort4*>(outT + (size_t)o * BATCH + chunk * BC + half * 4) = ov;
    }
}

// K3: outT [OW][BATCH] bf16 -> out [BATCH][OW] f32 (tiled transpose + cast)
__global__ __launch_bounds__(256) void k_transpose_out(
        const unsigned short* __restrict__ outT, float* __restrict__ out) {
    __shared__ float tile[64][65];          // [o_local][b_local]
    const int o0 = blockIdx.x * 64;
    const int b0 = blockIdx.y * 64;
    const int t  = threadIdx.x;
    const int r  = t >> 4;
    const int s  = t & 15;
    #pragma unroll
    for (int it = 0; it < 4; ++it) {
        const int ol = r + 16 * it;
        const ushort4 v = *reinterpret_cast<const ushort4*>(
            outT + (size_t)(o0 + ol) * BATCH + b0 + s * 4);
        tile[ol][s * 4 + 0] = __uint_as_float((unsigned)v.x << 16);
        tile[ol][s * 4 + 1] = __uint_as_float((unsigned)v.y << 16);
        tile[ol][s * 4 + 2] = __uint_as_float((unsigned)v.z << 16);
        tile[ol][s * 4 + 3] = __uint_as_float((unsigned)v.w << 16);
    }
    __syncthreads();
    #pragma unroll
    for (int it = 0; it < 4; ++it) {
        const int bl = r + 16 * it;
        float4 v;
        v.x = tile[s * 4 + 0][bl];
        v.y = tile[s * 4 + 1][bl];
        v.z = tile[s * 4 + 2][bl];
        v.w = tile[s * 4 + 3][bl];
        *reinterpret_cast<float4*>(out + (size_t)(b0 + bl) * OW + o0 + s * 4) = v;
    }
}

// Fallback (correctness-only) if ws is too small for staging.
__global__ __launch_bounds__(256) void k_naive(
        const float* __restrict__ x, const int* __restrict__ sel,
        const float* __restrict__ w, const float* __restrict__ biases,
        float* __restrict__ out) {
    __shared__ int   s_idx[PC];
    __shared__ float s_wa[PC];
    const int o = blockIdx.x;
    const int t = threadIdx.x;
    if (t < PC) {
        s_idx[t] = sel[o * PC + t];
        s_wa[t]  = sigmoidf_(w[o * PC + t]);
    }
    __syncthreads();
    const int b4 = t * 4;
    float a[4] = {0.f, 0.f, 0.f, 0.f};
    for (int p = 0; p < PC; ++p) {
        const int   idx = s_idx[p];
        const float wa  = s_wa[p];
        #pragma unroll
        for (int k = 0; k < 4; ++k)
            a[k] = fmaf(wa, x[(size_t)(b4 + k) * IW + idx], a[k]);
    }
    const float bo = biases[o];
    #pragma unroll
    for (int k = 0; k < 4; ++k)
        out[(size_t)(b4 + k) * OW + o] = sigmoidf_(a[k] - bo);
}

extern "C" void kernel_launch(void* const* d_in, const int* in_sizes, int n_in,
                              void* d_out, int out_size, void* d_ws, size_t ws_size,
                              hipStream_t stream) {
    const float* x      = (const float*)d_in[0];
    const int*   sel    = (const int*)d_in[1];
    const float* w      = (const float*)d_in[2];
    const float* biases = (const float*)d_in[3];
    float*       out    = (float*)d_out;

    const size_t xC_bytes   = (size_t)IW * BATCH * 2;        // 8 MB
    const size_t outT_bytes = (size_t)OW * BATCH * 2;        // 8 MB
    const size_t pt_bytes   = (size_t)OW * PC * sizeof(int2); // 2 MB

    if (ws_size >= xC_bytes + outT_bytes + pt_bytes) {
        unsigned short* xC   = (unsigned short*)d_ws;
        unsigned short* outT = (unsigned short*)((char*)d_ws + xC_bytes);
        int2*           pT   = (int2*)((char*)d_ws + xC_bytes + outT_bytes);
        k_transpose_cast<<<dim3(IW / 64, BATCH / 64), 256, 0, stream>>>(x, xC);
        k_prep_params<<<dim3(OW * PC / 256), 256, 0, stream>>>(sel, w, pT);
        k_gather_lds<<<dim3(NCHUNK * OSPLIT), 1024, 0, stream>>>(xC, pT, biases, outT);
        k_transpose_out<<<dim3(OW / 64, BATCH / 64), 256, 0, stream>>>(outT, out);
    } else {
        k_naive<<<OW, 256, 0, stream>>>(x, sel, w, biases, out);
    }
}